// Round 1
// baseline (1129.103 us; speedup 1.0000x reference)
//
#include <hip/hip_runtime.h>
#include <math.h>

#define NB    8
#define NQ    200
#define NCLS  81
#define HM    256
#define WM    256
#define SH    192   // scaled_h (crop rows)
#define SW    256   // scaled_w (crop cols)
#define OH    384   // origin_h
#define OW    512   // origin_w
#define NTOP  100
#define MIN_SCORE 0.1

__device__ __forceinline__ float sigf(float x) {
    float e = __expf(-x);                    // v_exp_f32 (fast, ~2 ulp)
    return __builtin_amdgcn_rcpf(1.0f + e);  // v_rcp_f32 (~1 ulp); sigmoid in (0,1)
}

// Kernel 1: per (b,q) softmax score + argmax class. Double precision so that
// "score > 0.1" validity matches the numpy reference (a flip costs absmax~80).
__global__ void k_scores(const float* __restrict__ cp,
                         double* __restrict__ sc, int* __restrict__ cls) {
    int i = blockIdx.x * blockDim.x + threadIdx.x;
    if (i >= NB * NQ) return;
    const float* p = cp + (size_t)i * NCLS;
    float l[NCLS];
    #pragma unroll
    for (int c = 0; c < NCLS; ++c) l[c] = p[c];
    double M = (double)l[0];
    for (int c = 1; c < NCLS; ++c) M = fmax(M, (double)l[c]);
    double Z = 0.0;
    for (int c = 0; c < NCLS; ++c) Z += exp((double)l[c] - M);
    float best = l[0]; int bi = 0;
    for (int c = 1; c < NCLS - 1; ++c)      // drop last class for score/argmax
        if (l[c] > best) { best = l[c]; bi = c; }
    sc[i]  = exp((double)best - M) / Z;
    cls[i] = bi;
}

// Kernel 2: exact top-k (descending, ties -> lower index) via rank counting.
// One block per batch; 200 elements -> O(200^2) trivial.
__global__ void k_topk(const double* __restrict__ sc, const int* __restrict__ cls,
                       float* __restrict__ out_scores, float* __restrict__ out_classes,
                       float* __restrict__ out_valid,
                       int* __restrict__ top_q, float* __restrict__ top_vf) {
    int b = blockIdx.x;
    __shared__ double s[NQ];
    int t = threadIdx.x;
    if (t < NQ) s[t] = sc[b * NQ + t];
    __syncthreads();
    if (t < NQ) {
        double mine = s[t];
        int rank = 0;
        for (int j = 0; j < NQ; ++j) {
            double v = s[j];
            rank += (v > mine) || (v == mine && j < t);
        }
        if (rank < NTOP) {
            int o = b * NTOP + rank;
            bool valid = mine > MIN_SCORE;
            out_scores[o]  = valid ? (float)mine : 0.0f;
            out_classes[o] = valid ? (float)cls[b * NQ + t] : -1.0f;
            out_valid[o]   = valid ? 1.0f : 0.0f;
            top_q[o]  = t;
            top_vf[o] = valid ? 1.0f : 0.0f;
        }
    }
}

// Kernel 3: gather mask -> sigmoid -> crop(192x256) -> 2x bilinear -> *valid.
// jax.image.resize 2x bilinear == clamp-to-edge bilinear at u=(o+0.5)/2-0.5.
// One block per output row of one mask: grid(OH, NB*NTOP), block OW=512.
__global__ void k_resize(const float* __restrict__ mask_preds,
                         const int* __restrict__ top_q,
                         const float* __restrict__ top_vf,
                         float* __restrict__ out_masks) {
    int m = blockIdx.y;                 // 0..799 (b*100 + k)
    int y = blockIdx.x;                 // 0..383
    int x = threadIdx.x;                // 0..511
    int b = m / NTOP;
    int q = top_q[m];
    float vf = top_vf[m];

    float uy  = y * 0.5f - 0.25f;
    float fyf = floorf(uy);
    float ty  = uy - fyf;               // 0.75 (even y) / 0.25 (odd y)
    int  fy   = (int)fyf;
    int  y0   = min(max(fy, 0), SH - 1);
    int  y1   = min(max(fy + 1, 0), SH - 1);

    const float* base = mask_preds + ((size_t)(b * NQ + q) * HM) * WM;
    const float* r0 = base + (size_t)y0 * WM;
    const float* r1 = base + (size_t)y1 * WM;

    float ux  = x * 0.5f - 0.25f;
    float fxf = floorf(ux);
    float tx  = ux - fxf;
    int  fx   = (int)fxf;
    int  x0   = min(max(fx, 0), SW - 1);
    int  x1   = min(max(fx + 1, 0), SW - 1);

    float s00 = sigf(r0[x0]);
    float s01 = sigf(r0[x1]);
    float s10 = sigf(r1[x0]);
    float s11 = sigf(r1[x1]);

    float top = s00 + tx * (s01 - s00);
    float bot = s10 + tx * (s11 - s10);
    float v   = top + ty * (bot - top);

    out_masks[((size_t)m * OH + y) * OW + x] = v * vf;
}

extern "C" void kernel_launch(void* const* d_in, const int* in_sizes, int n_in,
                              void* d_out, int out_size, void* d_ws, size_t ws_size,
                              hipStream_t stream) {
    (void)in_sizes; (void)n_in; (void)out_size; (void)ws_size;
    const float* mask_preds  = (const float*)d_in[0];
    const float* class_preds = (const float*)d_in[1];
    // d_in[2..5] are the (fixed) scalars 192,256,384,512 — compiled in.

    float* out        = (float*)d_out;
    float* out_masks  = out;                                    // 8*100*384*512
    float* out_scores = out + (size_t)NB * NTOP * OH * OW;      // 800
    float* out_classes= out_scores + NB * NTOP;                 // 800 (as float)
    float* out_valid  = out_classes + NB * NTOP;                // 800 (as float)

    char* ws = (char*)d_ws;
    double* sc    = (double*)ws;                                // 1600 * 8B
    int*    cls   = (int*)(ws + 1600 * 8);                      // 1600 * 4B
    int*    top_q = (int*)(ws + 1600 * 8 + 1600 * 4);           // 800  * 4B
    float*  top_vf= (float*)(ws + 1600 * 8 + 1600 * 4 + 800*4); // 800  * 4B

    k_scores<<<dim3((NB * NQ + 255) / 256), dim3(256), 0, stream>>>(class_preds, sc, cls);
    k_topk  <<<dim3(NB), dim3(256), 0, stream>>>(sc, cls, out_scores, out_classes,
                                                 out_valid, top_q, top_vf);
    k_resize<<<dim3(OH, NB * NTOP), dim3(OW), 0, stream>>>(mask_preds, top_q, top_vf,
                                                           out_masks);
}